// Round 1
// baseline (358.871 us; speedup 1.0000x reference)
//
#include <hip/hip_runtime.h>

// out[b,c,h,w] = x[b,c,h,w] * (1 - mask[b,0,h,w])   (MASK_VALUE == 0)
// B=64, C=3, H=W=512. Pure memory-bound elementwise blend.
//
// Grid layout: gridDim = (HW/4/256, C, B), block = 256 threads.
//   - each thread processes one float4 (16 B) -> ideal coalescing
//   - mask plane index = blockIdx.z  (no integer div/mod anywhere)
//   - HW = 2^18 divisible by 4*256, so no bounds checks needed.

#define HW   (512 * 512)        // 262144 elements per plane
#define C_   3
#define B_   64

__global__ __launch_bounds__(256) void random_mask_blend(
    const float4* __restrict__ x,     // B*C*HW/4 float4s
    const float4* __restrict__ mask,  // B*1*HW/4 float4s
    float4* __restrict__ out)
{
    const int vec_in_plane = blockIdx.x * blockDim.x + threadIdx.x; // [0, HW/4)
    const int c = blockIdx.y;
    const int b = blockIdx.z;

    const long long x_idx = ((long long)(b * C_ + c) * (HW / 4)) + vec_in_plane;
    const long long m_idx = ((long long)b * (HW / 4)) + vec_in_plane;

    const float4 xv = x[x_idx];
    const float4 mv = mask[m_idx];

    float4 ov;
    ov.x = xv.x * (1.0f - mv.x);
    ov.y = xv.y * (1.0f - mv.y);
    ov.z = xv.z * (1.0f - mv.z);
    ov.w = xv.w * (1.0f - mv.w);

    out[x_idx] = ov;
}

extern "C" void kernel_launch(void* const* d_in, const int* in_sizes, int n_in,
                              void* d_out, int out_size, void* d_ws, size_t ws_size,
                              hipStream_t stream) {
    const float4* x    = (const float4*)d_in[0];
    const float4* mask = (const float4*)d_in[1];
    float4* out        = (float4*)d_out;

    // HW/4 = 65536 vec4 per plane; 256 threads/block -> 256 blocks in x.
    dim3 grid(HW / 4 / 256, C_, B_);
    dim3 block(256);
    random_mask_blend<<<grid, block, 0, stream>>>(x, mask, out);
}

// Round 3
// 348.310 us; speedup vs baseline: 1.0303x; 1.0303x over previous
//
#include <hip/hip_runtime.h>

// out[b,c,h,w] = x[b,c,h,w] * (1 - mask[b,0,h,w])   (MASK_VALUE == 0)
// B=64, C=3, H=W=512. Pure memory-bound elementwise blend.
//
// R3 = R2 with native clang vector type (HIP's float4 is a struct and
// __builtin_nontemporal_* rejects it; ext_vector_type(4) is accepted).
//
// Structure: one thread owns one (b, hw-vec4) position and processes ALL
// 3 channels. The mask float4 is loaded exactly once from HBM by construction
// (no reliance on L2 absorbing cross-block re-reads; mask=67MB > 32MB agg L2).
// Guaranteed minimal traffic: 201 MB (x) + 67 MB (mask) + 201 MB (out) = 470 MB.
// All data is single-touch -> nontemporal loads/stores to avoid L2 pollution.
//
// Grid: (HW/4/256, B) blocks of 256. HW = 2^18, so HW/4/256 = 256 exactly.

#define HW   (512 * 512)        // 262144 elements per plane
#define C_   3
#define B_   64
#define VPP  (HW / 4)           // 65536 vec4s per plane

typedef float fvec4 __attribute__((ext_vector_type(4)));

__global__ __launch_bounds__(256) void random_mask_blend(
    const fvec4* __restrict__ x,     // B*C*VPP vec4s
    const fvec4* __restrict__ mask,  // B*1*VPP vec4s
    fvec4* __restrict__ out)
{
    const int v = blockIdx.x * blockDim.x + threadIdx.x;  // [0, VPP)
    const int b = blockIdx.y;

    const fvec4 mv = __builtin_nontemporal_load(&mask[(long long)b * VPP + v]);
    const fvec4 w = 1.0f - mv;      // computed once, reused for all 3 channels

    const long long base = ((long long)b * C_) * VPP + v;
#pragma unroll
    for (int c = 0; c < C_; ++c) {
        const long long idx = base + (long long)c * VPP;
        const fvec4 xv = __builtin_nontemporal_load(&x[idx]);
        __builtin_nontemporal_store(xv * w, &out[idx]);
    }
}

extern "C" void kernel_launch(void* const* d_in, const int* in_sizes, int n_in,
                              void* d_out, int out_size, void* d_ws, size_t ws_size,
                              hipStream_t stream) {
    const fvec4* x    = (const fvec4*)d_in[0];
    const fvec4* mask = (const fvec4*)d_in[1];
    fvec4* out        = (fvec4*)d_out;

    dim3 grid(VPP / 256, B_);   // (256, 64)
    dim3 block(256);
    random_mask_blend<<<grid, block, 0, stream>>>(x, mask, out);
}

// Round 4
// 339.420 us; speedup vs baseline: 1.0573x; 1.0262x over previous
//
#include <hip/hip_runtime.h>

// out[b,c,h,w] = x[b,c,h,w] * (1 - mask[b,0,h,w])   (MASK_VALUE == 0)
// B=64, C=3, H=W=512. Pure memory-bound elementwise blend.
//
// R4 = R3 + data-dependent x-load skip: mask is exactly {0,1} and covers
// huge contiguous regions (curtains/center/border). Where all 4 mask vals
// of a thread are 1, out = 0 and x is never loaded -> exec-masked lanes
// don't fetch their cachelines. Expected ~35% of x reads skipped (~70 MB).
//
// Guaranteed traffic: 201 MB (out) + 67 MB (mask) + ~0.65*201 MB (x) ~ 400 MB.
// All data single-touch -> nontemporal loads/stores.
//
// Grid: (HW/4/256, B) blocks of 256. HW = 2^18, so HW/4/256 = 256 exactly.

#define HW   (512 * 512)        // 262144 elements per plane
#define C_   3
#define B_   64
#define VPP  (HW / 4)           // 65536 vec4s per plane

typedef float fvec4 __attribute__((ext_vector_type(4)));

__global__ __launch_bounds__(256) void random_mask_blend(
    const fvec4* __restrict__ x,     // B*C*VPP vec4s
    const fvec4* __restrict__ mask,  // B*1*VPP vec4s
    fvec4* __restrict__ out)
{
    const int v = blockIdx.x * blockDim.x + threadIdx.x;  // [0, VPP)
    const int b = blockIdx.y;

    const fvec4 mv = __builtin_nontemporal_load(&mask[(long long)b * VPP + v]);
    const long long base = ((long long)b * C_) * VPP + v;

    // Fully-masked thread: out = 0 for all 3 channels, skip the x loads.
    if (mv.x + mv.y + mv.z + mv.w == 4.0f) {
        const fvec4 z = {0.0f, 0.0f, 0.0f, 0.0f};
#pragma unroll
        for (int c = 0; c < C_; ++c)
            __builtin_nontemporal_store(z, &out[base + (long long)c * VPP]);
    } else {
        const fvec4 w = 1.0f - mv;
#pragma unroll
        for (int c = 0; c < C_; ++c) {
            const long long idx = base + (long long)c * VPP;
            const fvec4 xv = __builtin_nontemporal_load(&x[idx]);
            __builtin_nontemporal_store(xv * w, &out[idx]);
        }
    }
}

extern "C" void kernel_launch(void* const* d_in, const int* in_sizes, int n_in,
                              void* d_out, int out_size, void* d_ws, size_t ws_size,
                              hipStream_t stream) {
    const fvec4* x    = (const fvec4*)d_in[0];
    const fvec4* mask = (const fvec4*)d_in[1];
    fvec4* out        = (fvec4*)d_out;

    dim3 grid(VPP / 256, B_);   // (256, 64)
    dim3 block(256);
    random_mask_blend<<<grid, block, 0, stream>>>(x, mask, out);
}